// Round 2
// baseline (1266.662 us; speedup 1.0000x reference)
//
#include <hip/hip_runtime.h>
#include <hip/hip_bf16.h>

// ---------------- problem constants ----------------
constexpr int B = 64;
constexpr int NG = 16;
constexpr int NSH = 112;
constexpr int N = 128;          // nodes per graph
constexpr int NN = B * N;       // 8192 total nodes
constexpr int L = 5;

// ---------------- workspace layout (float offsets) ----------------
constexpr int OFF_H     = 0;                    // [8192][32]
constexpr int OFF_P     = OFF_H + NN * 32;      // [8192][2]
constexpr int OFF_TEMB0 = OFF_P + NN * 2;       // [64][32]
constexpr int OFF_TEMB1 = OFF_TEMB0 + B * 32;
constexpr int OFF_HA    = OFF_TEMB1 + B * 32;   // [8192][32]  (h[dst]-term + temb-term + b_msg1)
constexpr int OFF_HB    = OFF_HA + NN * 32;     // [8192][32]  (h[src]-term)
constexpr int OFF_AGH   = OFF_HB + NN * 32;     // [8192][32]
constexpr int OFF_AGP   = OFF_AGH + NN * 32;    // [8192][2]

// ---------------- math helpers ----------------
__device__ __forceinline__ float fsigmoid(float x) {
    return __builtin_amdgcn_rcpf(1.0f + __expf(-x));
}
__device__ __forceinline__ float fsilu(float x) { return x * fsigmoid(x); }

// ---------------- setup: init h / p / temb0 ----------------
__global__ __launch_bounds__(256) void setup_kernel(
    const float* __restrict__ pos, const int* __restrict__ timesteps,
    const float* __restrict__ goal_pos,
    const float* __restrict__ W_hin, const float* __restrict__ b_hin,
    float* __restrict__ ws)
{
    int idx = blockIdx.x * 256 + threadIdx.x;

    if (idx < NN * 32) {                       // h init: goals use W_hin row 0, shelves row 1
        int c = idx & 31; int node = idx >> 5; int local = node & 127;
        int row = (local < NG) ? 0 : 1;
        ws[OFF_H + idx] = W_hin[row * 32 + c] + b_hin[c];
        return;
    }
    idx -= NN * 32;
    if (idx < NN * 2) {                        // p init
        int d = idx & 1; int node = idx >> 1; int g = node >> 7; int local = node & 127;
        float v = (local < NG) ? goal_pos[local * 2 + d]
                               : pos[(g * NSH + (local - NG)) * 2 + d];
        ws[OFF_P + idx] = v;
        return;
    }
    idx -= NN * 2;
    if (idx < B * 32) {                        // sinusoidal timestep embedding (precise math, one-time)
        int j = idx & 31; int g = idx >> 5;
        float t = (float)timesteps[g];
        int jj = (j < 16) ? j : (j - 16);
        float freq = expf(-logf(10000.0f) * (float)jj / 16.0f);
        float ang = t * freq;
        ws[OFF_TEMB0 + idx] = (j < 16) ? cosf(ang) : sinf(ang);
    }
}

// ---------------- per-layer node precompute: HA, HB ----------------
// HA[node][c] = sum_k h[node][k]*W1[k][c] + sum_k temb[g][k]*W1[65+k][c] + b1[c]
// HB[node][c] = sum_k h[node][k]*W1[32+k][c]
__global__ __launch_bounds__(256) void pre_kernel(
    const float* __restrict__ R,
    const float* __restrict__ W_msg1, const float* __restrict__ b_msg1,
    const float* __restrict__ tembIn, int layer)
{
    int tid = blockIdx.x * 256 + threadIdx.x;   // 0 .. 262143
    int c = tid & 31; int node = tid >> 5; int g = node >> 7;
    const float* __restrict__ W1 = W_msg1 + layer * 97 * 32;
    float accA = b_msg1[layer * 32 + c];
    float accB = 0.f;
#pragma unroll
    for (int k = 0; k < 32; ++k) {
        float hk = R[OFF_H + node * 32 + k];
        accA += hk * W1[k * 32 + c];
        accB += hk * W1[(32 + k) * 32 + c];
    }
#pragma unroll
    for (int k = 0; k < 32; ++k)
        accA += tembIn[g * 32 + k] * W1[(65 + k) * 32 + c];
    ((float*)R)[OFF_HA + tid] = accA;
    ((float*)R)[OFF_HB + tid] = accB;
}

// ---------------- edge kernel: messages + gated aggregation ----------------
// grid: 64 graphs x 8 dst-tiles (16 dst each) = 512 blocks, 256 threads.
// thread t: dst = t>>4 within tile, handles srcs {t&15, +16, ...} (8 each).
__global__ __launch_bounds__(256, 2) void edge_kernel(
    const float* __restrict__ R,
    const float* __restrict__ W_msg2, const float* __restrict__ b_msg2,
    const float* __restrict__ W_att, const float* __restrict__ b_att,
    const float* __restrict__ W_pos1, const float* __restrict__ b_pos1,
    const float* __restrict__ W_pos2, const float* __restrict__ b_pos2,
    const float* __restrict__ W_msg1,
    float* __restrict__ aggh, float* __restrict__ aggp, int layer)
{
    __shared__ float sHB[128][33];
    __shared__ float sHA[16][33];
    __shared__ float sP[128][2];

    const int t = threadIdx.x;
    const int bx = blockIdx.x;
    const int g = bx >> 3, dt = bx & 7;
    const int gbase = g * 128;

    for (int i = t; i < 128 * 32; i += 256) {
        int r = i >> 5, c = i & 31;
        sHB[r][c] = R[OFF_HB + (gbase + r) * 32 + c];
    }
    for (int i = t; i < 16 * 32; i += 256) {
        int r = i >> 5, c = i & 31;
        sHA[r][c] = R[OFF_HA + (gbase + dt * 16 + r) * 32 + c];
    }
    for (int i = t; i < 256; i += 256)
        sP[i >> 1][i & 1] = R[OFF_P + gbase * 2 + i];
    __syncthreads();

    const int dl = t >> 4;        // 0..15
    const int lane16 = t & 15;
    const int dloc = dt * 16 + dl;
    const float pxd = sP[dloc][0], pyd = sP[dloc][1];

    const float* __restrict__ Wm2 = W_msg2 + layer * 1024;
    const float* __restrict__ bm2 = b_msg2 + layer * 32;
    const float* __restrict__ watt = W_att + layer * 32;
    const float batt = b_att[layer];
    const float* __restrict__ Wp1 = W_pos1 + layer * 1024;
    const float* __restrict__ bp1 = b_pos1 + layer * 32;
    const float* __restrict__ wp2 = W_pos2 + layer * 32;
    const float bp2 = b_pos2[layer];
    const float* __restrict__ wr = W_msg1 + layer * 97 * 32 + 64 * 32;  // radial row

    float ha[32];
#pragma unroll
    for (int c = 0; c < 32; ++c) ha[c] = sHA[dl][c];

    float agh[32];
#pragma unroll
    for (int c = 0; c < 32; ++c) agh[c] = 0.f;
    float apx = 0.f, apy = 0.f;

#pragma unroll 1
    for (int s8 = 0; s8 < 8; ++s8) {
        const int src = lane16 + (s8 << 4);
        const float dx = pxd - sP[src][0];
        const float dy = pyd - sP[src][1];
        const float radial = dx * dx + dy * dy;
        const float inv = __builtin_amdgcn_rcpf(__builtin_amdgcn_sqrtf(radial) + 1e-6f);
        const float pnx = dx * inv, pny = dy * inv;

        float m1[32];
#pragma unroll
        for (int c = 0; c < 32; ++c)
            m1[c] = fsilu(ha[c] + sHB[src][c] + radial * wr[c]);

        float m2[32];
#pragma unroll
        for (int c = 0; c < 32; ++c) m2[c] = bm2[c];
#pragma unroll
        for (int k = 0; k < 32; ++k) {
            const float mk = m1[k];
#pragma unroll
            for (int c = 0; c < 32; ++c) m2[c] += mk * Wm2[k * 32 + c];
        }
        float attz = batt;
#pragma unroll
        for (int c = 0; c < 32; ++c) { m2[c] = fsilu(m2[c]); attz += m2[c] * watt[c]; }
        const float att = fsigmoid(attz);
#pragma unroll
        for (int c = 0; c < 32; ++c) m2[c] *= att;

        float q[32];
#pragma unroll
        for (int c = 0; c < 32; ++c) q[c] = bp1[c];
#pragma unroll
        for (int k = 0; k < 32; ++k) {
            const float mk = m2[k];
#pragma unroll
            for (int c = 0; c < 32; ++c) q[c] += mk * Wp1[k * 32 + c];
        }
        float pw = bp2;
#pragma unroll
        for (int c = 0; c < 32; ++c) pw += fsilu(q[c]) * wp2[c];

#pragma unroll
        for (int c = 0; c < 32; ++c) agh[c] += m2[c];
        apx += pnx * pw;
        apy += pny * pw;
    }

    // reduce across the 16 lanes sharing one dst (lanes differ in bits 0..3 only)
#pragma unroll
    for (int off = 8; off > 0; off >>= 1) {
#pragma unroll
        for (int c = 0; c < 32; ++c) agh[c] += __shfl_xor(agh[c], off);
        apx += __shfl_xor(apx, off);
        apy += __shfl_xor(apy, off);
    }
    if (lane16 == 0) {
        const int node = gbase + dloc;
#pragma unroll
        for (int c = 0; c < 32; ++c) aggh[node * 32 + c] = agh[c];
        aggp[node * 2 + 0] = apx * (1.0f / 128.0f);
        aggp[node * 2 + 1] = apy * (1.0f / 128.0f);
    }
}

// ---------------- node update (layers 0..3): h, p, temb ----------------
__global__ __launch_bounds__(256) void node_kernel(
    float* ws,
    const float* __restrict__ W_node1, const float* __restrict__ b_node1,
    const float* __restrict__ W_node2, const float* __restrict__ b_node2,
    const float* __restrict__ W_t, const float* __restrict__ b_t,
    int layer)
{
    const int tid = blockIdx.x * 256 + threadIdx.x;   // node id, 0..8191
    const float* Wn1 = W_node1 + layer * 2048;
    const float* bn1 = b_node1 + layer * 32;
    const float* Wn2 = W_node2 + layer * 1024;
    const float* bn2 = b_node2 + layer * 32;

    float h[32], ag[32];
#pragma unroll
    for (int k = 0; k < 32; ++k) {
        h[k]  = ws[OFF_H + tid * 32 + k];
        ag[k] = ws[OFF_AGH + tid * 32 + k];
    }
    float u1[32];
#pragma unroll
    for (int c = 0; c < 32; ++c) u1[c] = bn1[c];
#pragma unroll
    for (int k = 0; k < 32; ++k) {
        const float hk = h[k], agk = ag[k];
#pragma unroll
        for (int c = 0; c < 32; ++c)
            u1[c] += hk * Wn1[k * 32 + c] + agk * Wn1[(32 + k) * 32 + c];
    }
#pragma unroll
    for (int c = 0; c < 32; ++c) u1[c] = fsilu(u1[c]);
#pragma unroll
    for (int c = 0; c < 32; ++c) {
        float u = bn2[c];
#pragma unroll
        for (int k = 0; k < 32; ++k) u += u1[k] * Wn2[k * 32 + c];
        float hn = (u > 0.f ? u : 0.01f * u) + h[c];
        ws[OFF_H + tid * 32 + c] = hn;
    }
    // p += aggr_p
    ws[OFF_P + tid * 2 + 0] += ws[OFF_AGP + tid * 2 + 0];
    ws[OFF_P + tid * 2 + 1] += ws[OFF_AGP + tid * 2 + 1];

    // temb update (double-buffered)
    if (tid < B * 32) {
        const int g = tid >> 5, c2 = tid & 31;
        const float* Wt = W_t + layer * 1024;
        const float* tin = ws + ((layer & 1) ? OFF_TEMB1 : OFF_TEMB0) + g * 32;
        float acc = b_t[layer * 32 + c2];
#pragma unroll
        for (int k = 0; k < 32; ++k) acc += tin[k] * Wt[k * 32 + c2];
        ws[((layer & 1) ? OFF_TEMB0 : OFF_TEMB1) + tid] = fsilu(acc);
    }
}

// ---------------- final: p += aggr_p for shelves, emit fp32 ----------------
__global__ __launch_bounds__(256) void out_kernel(const float* __restrict__ R,
                                                  float* __restrict__ out)
{
    const int o = blockIdx.x * 256 + threadIdx.x;     // 0..14335
    if (o >= B * NSH * 2) return;
    const int d = o & 1;
    const int s = (o >> 1) % NSH;
    const int b = (o >> 1) / NSH;
    const int node = b * 128 + NG + s;
    out[o] = R[OFF_P + node * 2 + d] + R[OFF_AGP + node * 2 + d];
}

// ---------------- launch ----------------
extern "C" void kernel_launch(void* const* d_in, const int* in_sizes, int n_in,
                              void* d_out, int out_size, void* d_ws, size_t ws_size,
                              hipStream_t stream)
{
    const float* pos      = (const float*)d_in[0];
    const int*   tsteps   = (const int*)d_in[1];
    const float* goal_pos = (const float*)d_in[2];
    const float* W_hin    = (const float*)d_in[3];
    const float* b_hin    = (const float*)d_in[4];
    const float* W_msg1   = (const float*)d_in[5];
    const float* b_msg1   = (const float*)d_in[6];
    const float* W_msg2   = (const float*)d_in[7];
    const float* b_msg2   = (const float*)d_in[8];
    const float* W_att    = (const float*)d_in[9];
    const float* b_att    = (const float*)d_in[10];
    const float* W_pos1   = (const float*)d_in[11];
    const float* b_pos1   = (const float*)d_in[12];
    const float* W_pos2   = (const float*)d_in[13];
    const float* b_pos2   = (const float*)d_in[14];
    const float* W_node1  = (const float*)d_in[15];
    const float* b_node1  = (const float*)d_in[16];
    const float* W_node2  = (const float*)d_in[17];
    const float* b_node2  = (const float*)d_in[18];
    const float* W_t      = (const float*)d_in[19];
    const float* b_t      = (const float*)d_in[20];

    float* ws = (float*)d_ws;

    constexpr int setup_threads = NN * 32 + NN * 2 + B * 32;
    setup_kernel<<<(setup_threads + 255) / 256, 256, 0, stream>>>(
        pos, tsteps, goal_pos, W_hin, b_hin, ws);

    for (int l = 0; l < L; ++l) {
        const float* tembIn = ws + ((l & 1) ? OFF_TEMB1 : OFF_TEMB0);
        pre_kernel<<<NN * 32 / 256, 256, 0, stream>>>(ws, W_msg1, b_msg1, tembIn, l);
        edge_kernel<<<B * 8, 256, 0, stream>>>(ws, W_msg2, b_msg2, W_att, b_att,
                                               W_pos1, b_pos1, W_pos2, b_pos2, W_msg1,
                                               ws + OFF_AGH, ws + OFF_AGP, l);
        if (l < L - 1)
            node_kernel<<<NN / 256, 256, 0, stream>>>(ws, W_node1, b_node1, W_node2,
                                                      b_node2, W_t, b_t, l);
    }
    out_kernel<<<(B * NSH * 2 + 255) / 256, 256, 0, stream>>>(ws, (float*)d_out);
}

// Round 3
// 594.130 us; speedup vs baseline: 2.1320x; 2.1320x over previous
//
#include <hip/hip_runtime.h>
#include <hip/hip_bf16.h>

// ---------------- problem constants ----------------
constexpr int B = 64;
constexpr int NG = 16;
constexpr int NSH = 112;
constexpr int N = 128;          // nodes per graph
constexpr int NN = B * N;       // 8192 total nodes
constexpr int L = 5;

// ---------------- workspace layout (float offsets) ----------------
constexpr int OFF_H     = 0;                    // [8192][32] f32
constexpr int OFF_P     = OFF_H + NN * 32;      // [8192][2]  f32
constexpr int OFF_TEMB0 = OFF_P + NN * 2;       // [64][32]
constexpr int OFF_TEMB1 = OFF_TEMB0 + B * 32;
constexpr int OFF_HA    = OFF_TEMB1 + B * 32;   // [8192][32] f32 (h[dst]-term + temb-term + b_msg1)
constexpr int OFF_HB    = OFF_HA + NN * 32;     // [8192][32] stored as ushort bf16 (h[src]-term)
constexpr int OFF_AGH   = OFF_HB + NN * 32;     // [8192][32] f32
constexpr int OFF_AGP   = OFF_AGH + NN * 32;    // [8192][2]  f32

typedef __attribute__((ext_vector_type(8))) short bf16x8;
typedef __attribute__((ext_vector_type(4))) float f32x4;

// ---------------- math helpers ----------------
__device__ __forceinline__ float fsigmoid(float x) {
    return __builtin_amdgcn_rcpf(1.0f + __expf(-x));
}
__device__ __forceinline__ float fsilu(float x) { return x * fsigmoid(x); }
__device__ __forceinline__ short f2bfs(float f) {
    union { __hip_bfloat16 b; short s; } u; u.b = __float2bfloat16(f); return u.s;
}
__device__ __forceinline__ float bf2f(unsigned short u) {
    union { unsigned int i; float f; } v; v.i = ((unsigned int)u) << 16; return v.f;
}

// ---------------- setup: init h / p / temb0 ----------------
__global__ __launch_bounds__(256) void setup_kernel(
    const float* __restrict__ pos, const int* __restrict__ timesteps,
    const float* __restrict__ goal_pos,
    const float* __restrict__ W_hin, const float* __restrict__ b_hin,
    float* __restrict__ ws)
{
    int idx = blockIdx.x * 256 + threadIdx.x;

    if (idx < NN * 32) {                       // h init: goals use W_hin row 0, shelves row 1
        int c = idx & 31; int node = idx >> 5; int local = node & 127;
        int row = (local < NG) ? 0 : 1;
        ws[OFF_H + idx] = W_hin[row * 32 + c] + b_hin[c];
        return;
    }
    idx -= NN * 32;
    if (idx < NN * 2) {                        // p init
        int d = idx & 1; int node = idx >> 1; int g = node >> 7; int local = node & 127;
        float v = (local < NG) ? goal_pos[local * 2 + d]
                               : pos[(g * NSH + (local - NG)) * 2 + d];
        ws[OFF_P + idx] = v;
        return;
    }
    idx -= NN * 2;
    if (idx < B * 32) {                        // sinusoidal timestep embedding
        int j = idx & 31; int g = idx >> 5;
        float t = (float)timesteps[g];
        int jj = (j < 16) ? j : (j - 16);
        float freq = expf(-logf(10000.0f) * (float)jj / 16.0f);
        float ang = t * freq;
        ws[OFF_TEMB0 + idx] = (j < 16) ? cosf(ang) : sinf(ang);
    }
}

// ---------------- per-layer node precompute: HA (f32), HBh (bf16) ----------------
__global__ __launch_bounds__(256) void pre_kernel(
    float* __restrict__ R,
    const float* __restrict__ W_msg1, const float* __restrict__ b_msg1,
    const float* __restrict__ tembIn, int layer)
{
    int tid = blockIdx.x * 256 + threadIdx.x;   // 0 .. 262143
    int c = tid & 31; int node = tid >> 5; int g = node >> 7;
    const float* __restrict__ W1 = W_msg1 + layer * 97 * 32;
    float accA = b_msg1[layer * 32 + c];
    float accB = 0.f;
#pragma unroll
    for (int k = 0; k < 32; ++k) {
        float hk = R[OFF_H + node * 32 + k];
        accA += hk * W1[k * 32 + c];
        accB += hk * W1[(32 + k) * 32 + c];
    }
#pragma unroll
    for (int k = 0; k < 32; ++k)
        accA += tembIn[g * 32 + k] * W1[(65 + k) * 32 + c];
    R[OFF_HA + tid] = accA;
    ((unsigned short*)(R + OFF_HB))[tid] = (unsigned short)f2bfs(accB);
}

// ---------------- edge kernel (MFMA): messages + gated aggregation ----------------
// grid: 64 graphs x 32 dst-groups = 2048 blocks, 256 thr = 4 waves.
// wave w handles dst = dgrp*4 + w; iterates 2 src-halves of 64 srcs (lane=src).
__global__ __launch_bounds__(256, 4) void edge_kernel(
    float* __restrict__ R,
    const float* __restrict__ W_msg1,
    const float* __restrict__ W_msg2, const float* __restrict__ b_msg2,
    const float* __restrict__ W_att, const float* __restrict__ b_att,
    const float* __restrict__ W_pos1, const float* __restrict__ b_pos1,
    const float* __restrict__ W_pos2, const float* __restrict__ b_pos2,
    float* __restrict__ aggh, float* __restrict__ aggp, int layer)
{
    __shared__ unsigned short sHBh[128 * 40];   // bf16, row stride 40 (80B, 16B-aligned)
    __shared__ float sPx[128], sPy[128];
    __shared__ unsigned int mbuf[4 * 64 * 20];  // per-wave gated-m2 staging, row stride 20 dwords

    const int t = threadIdx.x;
    const int bx = blockIdx.x;
    const int g = bx >> 5;
    const int gbase = g * 128;

    // ---- stage HBh (graph's 128x32 bf16) + positions ----
    const unsigned short* HBH = (const unsigned short*)(R + OFF_HB);
#pragma unroll
    for (int ch = 0; ch < 2; ++ch) {
        int chunk = t + ch * 256;               // 512 chunks of 8 bf16
        int row = chunk >> 2, g4 = chunk & 3;
        uint4 v = *(const uint4*)(HBH + (gbase + row) * 32 + (g4 << 3));
        *(uint4*)(sHBh + row * 40 + (g4 << 3)) = v;
    }
    if (t < 128) {
        sPx[t] = R[OFF_P + (gbase + t) * 2];
        sPy[t] = R[OFF_P + (gbase + t) * 2 + 1];
    }
    __syncthreads();

    const int lane = t & 63, w = t >> 6;
    const int c = lane & 15;
    const int rg = lane >> 4;
    const int kk = rg << 3;
    const int dloc = ((bx & 31) << 2) | w;
    const int dstNode = gbase + dloc;

    // ---- resident weight fragments (bf16) ----
    const float* __restrict__ Wm2L = W_msg2 + layer * 1024;
    const float* __restrict__ Wp1L = W_pos1 + layer * 1024;
    bf16x8 WB1c0, WB1c1, WBpc0, WBpc1;
#pragma unroll
    for (int j = 0; j < 8; ++j) {
        WB1c0[j] = f2bfs(Wm2L[(kk + j) * 32 + c]);
        WB1c1[j] = f2bfs(Wm2L[(kk + j) * 32 + c + 16]);
        int pk = ((kk + j) & 1) * 16 + ((kk + j) >> 1);   // pi-permuted k for GEMM-2
        WBpc0[j] = f2bfs(Wp1L[pk * 32 + c]);
        WBpc1[j] = f2bfs(Wp1L[pk * 32 + c + 16]);
    }

    // ---- per-dst / per-lane constants ----
    float vha[8], vwr[8];
    {
        const float* haR = R + OFF_HA + dstNode * 32 + kk;
        const float* wrR = W_msg1 + layer * 97 * 32 + 64 * 32 + kk;
#pragma unroll
        for (int j = 0; j < 8; ++j) { vha[j] = haR[j]; vwr[j] = wrR[j]; }
    }
    const float vwatt0 = W_att[layer * 32 + c], vwatt1 = W_att[layer * 32 + c + 16];
    const float batt   = b_att[layer];
    const float vbm20  = b_msg2[layer * 32 + c], vbm21 = b_msg2[layer * 32 + c + 16];
    const float vbp10  = b_pos1[layer * 32 + c], vbp11 = b_pos1[layer * 32 + c + 16];
    const float vwp20  = W_pos2[layer * 32 + c], vwp21 = W_pos2[layer * 32 + c + 16];
    const float bp2    = b_pos2[layer];
    const float pxd = R[OFF_P + dstNode * 2], pyd = R[OFF_P + dstNode * 2 + 1];

    unsigned int* mb = mbuf + w * 64 * 20;

    float aghc0 = 0.f, aghc1 = 0.f, apx = 0.f, apy = 0.f, spnx = 0.f, spny = 0.f;

#pragma unroll 1
    for (int half = 0; half < 2; ++half) {
        // ---- phase 0: per-src geometry (lane = src within half) ----
        const int src = (half << 6) + lane;
        const float dx = pxd - sPx[src];
        const float dy = pyd - sPy[src];
        const float radial = dx * dx + dy * dy;
        const float inv = __builtin_amdgcn_rcpf(__builtin_amdgcn_sqrtf(radial) + 1e-6f);
        const float pnx = dx * inv, pny = dy * inv;
        spnx += pnx; spny += pny;

        // ---- phase 1: build m1 A-frags in place, GEMM-1 ----
        f32x4 acc0[4], acc1[4];
#pragma unroll
        for (int tt = 0; tt < 4; ++tt) {
            acc0[tt] = (f32x4){vbm20, vbm20, vbm20, vbm20};
            acc1[tt] = (f32x4){vbm21, vbm21, vbm21, vbm21};
        }
#pragma unroll
        for (int tt = 0; tt < 4; ++tt) {
            const float rad_t = __shfl(radial, c + (tt << 4));
            uint4 hraw = *(const uint4*)(sHBh + ((half << 6) + c + (tt << 4)) * 40 + kk);
            const unsigned short* hs = (const unsigned short*)&hraw;
            bf16x8 af;
#pragma unroll
            for (int j = 0; j < 8; ++j) {
                float x = vha[j] + bf2f(hs[j]) + rad_t * vwr[j];
                af[j] = f2bfs(fsilu(x));
            }
            acc0[tt] = __builtin_amdgcn_mfma_f32_16x16x32_bf16(af, WB1c0, acc0[tt], 0, 0, 0);
            acc1[tt] = __builtin_amdgcn_mfma_f32_16x16x32_bf16(af, WB1c1, acc1[tt], 0, 0, 0);
        }

        // ---- phase 2: silu, attention gate, agh, stage gated m2 (pi-packed bf16) ----
        float pa[16];
#pragma unroll
        for (int tt = 0; tt < 4; ++tt)
#pragma unroll
            for (int j = 0; j < 4; ++j) {
                float s0 = fsilu(acc0[tt][j]);
                float s1 = fsilu(acc1[tt][j]);
                acc0[tt][j] = s0; acc1[tt][j] = s1;
                pa[tt * 4 + j] = s0 * vwatt0 + s1 * vwatt1;
            }
#pragma unroll
        for (int off = 1; off < 16; off <<= 1)
#pragma unroll
            for (int i = 0; i < 16; ++i) pa[i] += __shfl_xor(pa[i], off);
#pragma unroll
        for (int tt = 0; tt < 4; ++tt)
#pragma unroll
            for (int j = 0; j < 4; ++j) {
                float att = fsigmoid(batt + pa[tt * 4 + j]);
                float g0 = acc0[tt][j] * att, g1 = acc1[tt][j] * att;
                aghc0 += g0; aghc1 += g1;
                unsigned int packed = ((unsigned int)(unsigned short)f2bfs(g1) << 16)
                                    | (unsigned short)f2bfs(g0);
                mb[(tt * 16 + rg * 4 + j) * 20 + c] = packed;
            }

        // ---- phase 3: GEMM-2 (q) from staged A-frags ----
        f32x4 q0[4], q1[4];
#pragma unroll
        for (int tt = 0; tt < 4; ++tt) {
            q0[tt] = (f32x4){vbp10, vbp10, vbp10, vbp10};
            q1[tt] = (f32x4){vbp11, vbp11, vbp11, vbp11};
        }
#pragma unroll
        for (int tt = 0; tt < 4; ++tt) {
            union { uint4 u; bf16x8 v; } qa;
            qa.u = *(const uint4*)(mb + (c + (tt << 4)) * 20 + (rg << 2));
            q0[tt] = __builtin_amdgcn_mfma_f32_16x16x32_bf16(qa.v, WBpc0, q0[tt], 0, 0, 0);
            q1[tt] = __builtin_amdgcn_mfma_f32_16x16x32_bf16(qa.v, WBpc1, q1[tt], 0, 0, 0);
        }

        // ---- phase 4: pw and weighted pd accumulation ----
#pragma unroll
        for (int tt = 0; tt < 4; ++tt)
#pragma unroll
            for (int j = 0; j < 4; ++j) {
                float s = fsilu(q0[tt][j]) * vwp20 + fsilu(q1[tt][j]) * vwp21;
                int r = tt * 16 + rg * 4 + j;
                apx += s * __shfl(pnx, r);
                apy += s * __shfl(pny, r);
            }
    }

    // ---- epilogue: reductions + stores ----
    aghc0 += __shfl_xor(aghc0, 16); aghc0 += __shfl_xor(aghc0, 32);
    aghc1 += __shfl_xor(aghc1, 16); aghc1 += __shfl_xor(aghc1, 32);
#pragma unroll
    for (int off = 1; off < 64; off <<= 1) {
        apx  += __shfl_xor(apx, off);
        apy  += __shfl_xor(apy, off);
        spnx += __shfl_xor(spnx, off);
        spny += __shfl_xor(spny, off);
    }
    if (lane < 16)       aggh[dstNode * 32 + lane] = aghc0;
    else if (lane < 32)  aggh[dstNode * 32 + lane] = aghc1;
    if (lane == 0) {
        aggp[dstNode * 2]     = (apx + bp2 * spnx) * (1.0f / 128.0f);
        aggp[dstNode * 2 + 1] = (apy + bp2 * spny) * (1.0f / 128.0f);
    }
}

// ---------------- node update (layers 0..3): h, p, temb ----------------
__global__ __launch_bounds__(256) void node_kernel(
    float* ws,
    const float* __restrict__ W_node1, const float* __restrict__ b_node1,
    const float* __restrict__ W_node2, const float* __restrict__ b_node2,
    const float* __restrict__ W_t, const float* __restrict__ b_t,
    int layer)
{
    const int tid = blockIdx.x * 256 + threadIdx.x;   // node id, 0..8191
    const float* Wn1 = W_node1 + layer * 2048;
    const float* bn1 = b_node1 + layer * 32;
    const float* Wn2 = W_node2 + layer * 1024;
    const float* bn2 = b_node2 + layer * 32;

    float h[32], ag[32];
#pragma unroll
    for (int k = 0; k < 32; ++k) {
        h[k]  = ws[OFF_H + tid * 32 + k];
        ag[k] = ws[OFF_AGH + tid * 32 + k];
    }
    float u1[32];
#pragma unroll
    for (int c = 0; c < 32; ++c) u1[c] = bn1[c];
#pragma unroll
    for (int k = 0; k < 32; ++k) {
        const float hk = h[k], agk = ag[k];
#pragma unroll
        for (int c = 0; c < 32; ++c)
            u1[c] += hk * Wn1[k * 32 + c] + agk * Wn1[(32 + k) * 32 + c];
    }
#pragma unroll
    for (int c = 0; c < 32; ++c) u1[c] = fsilu(u1[c]);
#pragma unroll
    for (int c = 0; c < 32; ++c) {
        float u = bn2[c];
#pragma unroll
        for (int k = 0; k < 32; ++k) u += u1[k] * Wn2[k * 32 + c];
        float hn = (u > 0.f ? u : 0.01f * u) + h[c];
        ws[OFF_H + tid * 32 + c] = hn;
    }
    ws[OFF_P + tid * 2 + 0] += ws[OFF_AGP + tid * 2 + 0];
    ws[OFF_P + tid * 2 + 1] += ws[OFF_AGP + tid * 2 + 1];

    if (tid < B * 32) {                                // temb update (double-buffered)
        const int g = tid >> 5, c2 = tid & 31;
        const float* Wt = W_t + layer * 1024;
        const float* tin = ws + ((layer & 1) ? OFF_TEMB1 : OFF_TEMB0) + g * 32;
        float acc = b_t[layer * 32 + c2];
#pragma unroll
        for (int k = 0; k < 32; ++k) acc += tin[k] * Wt[k * 32 + c2];
        ws[((layer & 1) ? OFF_TEMB0 : OFF_TEMB1) + tid] = fsilu(acc);
    }
}

// ---------------- final: p += aggr_p for shelves, emit fp32 ----------------
__global__ __launch_bounds__(256) void out_kernel(const float* __restrict__ R,
                                                  float* __restrict__ out)
{
    const int o = blockIdx.x * 256 + threadIdx.x;     // 0..14335
    if (o >= B * NSH * 2) return;
    const int d = o & 1;
    const int s = (o >> 1) % NSH;
    const int b = (o >> 1) / NSH;
    const int node = b * 128 + NG + s;
    out[o] = R[OFF_P + node * 2 + d] + R[OFF_AGP + node * 2 + d];
}

// ---------------- launch ----------------
extern "C" void kernel_launch(void* const* d_in, const int* in_sizes, int n_in,
                              void* d_out, int out_size, void* d_ws, size_t ws_size,
                              hipStream_t stream)
{
    const float* pos      = (const float*)d_in[0];
    const int*   tsteps   = (const int*)d_in[1];
    const float* goal_pos = (const float*)d_in[2];
    const float* W_hin    = (const float*)d_in[3];
    const float* b_hin    = (const float*)d_in[4];
    const float* W_msg1   = (const float*)d_in[5];
    const float* b_msg1   = (const float*)d_in[6];
    const float* W_msg2   = (const float*)d_in[7];
    const float* b_msg2   = (const float*)d_in[8];
    const float* W_att    = (const float*)d_in[9];
    const float* b_att    = (const float*)d_in[10];
    const float* W_pos1   = (const float*)d_in[11];
    const float* b_pos1   = (const float*)d_in[12];
    const float* W_pos2   = (const float*)d_in[13];
    const float* b_pos2   = (const float*)d_in[14];
    const float* W_node1  = (const float*)d_in[15];
    const float* b_node1  = (const float*)d_in[16];
    const float* W_node2  = (const float*)d_in[17];
    const float* b_node2  = (const float*)d_in[18];
    const float* W_t      = (const float*)d_in[19];
    const float* b_t      = (const float*)d_in[20];

    float* ws = (float*)d_ws;

    constexpr int setup_threads = NN * 32 + NN * 2 + B * 32;
    setup_kernel<<<(setup_threads + 255) / 256, 256, 0, stream>>>(
        pos, tsteps, goal_pos, W_hin, b_hin, ws);

    for (int l = 0; l < L; ++l) {
        const float* tembIn = ws + ((l & 1) ? OFF_TEMB1 : OFF_TEMB0);
        pre_kernel<<<NN * 32 / 256, 256, 0, stream>>>(ws, W_msg1, b_msg1, tembIn, l);
        edge_kernel<<<2048, 256, 0, stream>>>(ws, W_msg1, W_msg2, b_msg2, W_att, b_att,
                                              W_pos1, b_pos1, W_pos2, b_pos2,
                                              ws + OFF_AGH, ws + OFF_AGP, l);
        if (l < L - 1)
            node_kernel<<<NN / 256, 256, 0, stream>>>(ws, W_node1, b_node1, W_node2,
                                                      b_node2, W_t, b_t, l);
    }
    out_kernel<<<(B * NSH * 2 + 255) / 256, 256, 0, stream>>>(ws, (float*)d_out);
}

// Round 4
// 368.579 us; speedup vs baseline: 3.4366x; 1.6119x over previous
//
#include <hip/hip_runtime.h>
#include <hip/hip_bf16.h>

// ---------------- problem constants ----------------
constexpr int B = 64;
constexpr int NG = 16;
constexpr int NSH = 112;
constexpr int N = 128;          // nodes per graph
constexpr int NN = B * N;       // 8192 total nodes
constexpr int L = 5;

// ---------------- workspace layout (float offsets) ----------------
constexpr int OFF_H     = 0;                    // [8192][32] f32
constexpr int OFF_P     = OFF_H + NN * 32;      // [8192][2]  f32
constexpr int OFF_TEMB0 = OFF_P + NN * 2;       // [64][32]
constexpr int OFF_TEMB1 = OFF_TEMB0 + B * 32;
constexpr int OFF_HA    = OFF_TEMB1 + B * 32;   // [8192][32] f32 (h[dst]-term + temb-term + b_msg1)
constexpr int OFF_HB    = OFF_HA + NN * 32;     // [8192][32] stored as ushort bf16 (h[src]-term)
constexpr int OFF_AGH   = OFF_HB + NN * 32;     // [8192][32] f32
constexpr int OFF_AGP   = OFF_AGH + NN * 32;    // [8192][2]  f32

typedef __attribute__((ext_vector_type(8))) short bf16x8;
typedef __attribute__((ext_vector_type(4))) float f32x4;

// ---------------- math helpers ----------------
__device__ __forceinline__ float fsigmoid(float x) {
    return __builtin_amdgcn_rcpf(1.0f + __expf(-x));
}
__device__ __forceinline__ float fsilu(float x) { return x * fsigmoid(x); }
__device__ __forceinline__ short f2bfs(float f) {
    union { __hip_bfloat16 b; short s; } u; u.b = __float2bfloat16(f); return u.s;
}
__device__ __forceinline__ float bf2f(unsigned short u) {
    union { unsigned int i; float f; } v; v.i = ((unsigned int)u) << 16; return v.f;
}

// ---------------- setup: init h / p / temb0 ----------------
__global__ __launch_bounds__(256) void setup_kernel(
    const float* __restrict__ pos, const int* __restrict__ timesteps,
    const float* __restrict__ goal_pos,
    const float* __restrict__ W_hin, const float* __restrict__ b_hin,
    float* __restrict__ ws)
{
    int idx = blockIdx.x * 256 + threadIdx.x;

    if (idx < NN * 32) {                       // h init: goals use W_hin row 0, shelves row 1
        int c = idx & 31; int node = idx >> 5; int local = node & 127;
        int row = (local < NG) ? 0 : 1;
        ws[OFF_H + idx] = W_hin[row * 32 + c] + b_hin[c];
        return;
    }
    idx -= NN * 32;
    if (idx < NN * 2) {                        // p init
        int d = idx & 1; int node = idx >> 1; int g = node >> 7; int local = node & 127;
        float v = (local < NG) ? goal_pos[local * 2 + d]
                               : pos[(g * NSH + (local - NG)) * 2 + d];
        ws[OFF_P + idx] = v;
        return;
    }
    idx -= NN * 2;
    if (idx < B * 32) {                        // sinusoidal timestep embedding
        int j = idx & 31; int g = idx >> 5;
        float t = (float)timesteps[g];
        int jj = (j < 16) ? j : (j - 16);
        float freq = expf(-logf(10000.0f) * (float)jj / 16.0f);
        float ang = t * freq;
        ws[OFF_TEMB0 + idx] = (j < 16) ? cosf(ang) : sinf(ang);
    }
}

// ---------------- per-layer node precompute: HA (f32), HBh (bf16) ----------------
__global__ __launch_bounds__(256) void pre_kernel(
    float* __restrict__ R,
    const float* __restrict__ W_msg1, const float* __restrict__ b_msg1,
    const float* __restrict__ tembIn, int layer)
{
    int tid = blockIdx.x * 256 + threadIdx.x;   // 0 .. 262143
    int c = tid & 31; int node = tid >> 5; int g = node >> 7;
    const float* __restrict__ W1 = W_msg1 + layer * 97 * 32;
    float accA = b_msg1[layer * 32 + c];
    float accB = 0.f;
#pragma unroll
    for (int k = 0; k < 32; ++k) {
        float hk = R[OFF_H + node * 32 + k];
        accA += hk * W1[k * 32 + c];
        accB += hk * W1[(32 + k) * 32 + c];
    }
#pragma unroll
    for (int k = 0; k < 32; ++k)
        accA += tembIn[g * 32 + k] * W1[(65 + k) * 32 + c];
    R[OFF_HA + tid] = accA;
    ((unsigned short*)(R + OFF_HB))[tid] = (unsigned short)f2bfs(accB);
}

// ---------------- edge kernel (MFMA): messages + gated aggregation ----------------
// grid: 64 graphs x 32 dst-groups = 2048 blocks, 256 thr = 4 waves.
__global__ __launch_bounds__(256, 4) void edge_kernel(
    float* __restrict__ R,
    const float* __restrict__ W_msg1,
    const float* __restrict__ W_msg2, const float* __restrict__ b_msg2,
    const float* __restrict__ W_att, const float* __restrict__ b_att,
    const float* __restrict__ W_pos1, const float* __restrict__ b_pos1,
    const float* __restrict__ W_pos2, const float* __restrict__ b_pos2,
    float* __restrict__ aggh, float* __restrict__ aggp, int layer)
{
    __shared__ unsigned short sHBh[128 * 40];   // bf16, row stride 40 (80B, 16B-aligned)
    __shared__ float sPx[128], sPy[128];
    __shared__ unsigned int mbuf[4 * 64 * 20];  // per-wave gated-m2 staging, row stride 20 dwords

    const int t = threadIdx.x;
    const int bx = blockIdx.x;
    const int g = bx >> 5;
    const int gbase = g * 128;

    // ---- stage HBh (graph's 128x32 bf16) + positions ----
    const unsigned short* HBH = (const unsigned short*)(R + OFF_HB);
#pragma unroll
    for (int ch = 0; ch < 2; ++ch) {
        int chunk = t + ch * 256;               // 512 chunks of 8 bf16
        int row = chunk >> 2, g4 = chunk & 3;
        uint4 v = *(const uint4*)(HBH + (gbase + row) * 32 + (g4 << 3));
        *(uint4*)(sHBh + row * 40 + (g4 << 3)) = v;
    }
    if (t < 128) {
        sPx[t] = R[OFF_P + (gbase + t) * 2];
        sPy[t] = R[OFF_P + (gbase + t) * 2 + 1];
    }
    __syncthreads();

    const int lane = t & 63, w = t >> 6;
    const int c = lane & 15;
    const int rg = lane >> 4;
    const int kk = rg << 3;
    const int dloc = ((bx & 31) << 2) | w;
    const int dstNode = gbase + dloc;

    // ---- resident weight fragments (bf16) ----
    const float* __restrict__ Wm2L = W_msg2 + layer * 1024;
    const float* __restrict__ Wp1L = W_pos1 + layer * 1024;
    bf16x8 WB1c0, WB1c1, WBpc0, WBpc1;
#pragma unroll
    for (int j = 0; j < 8; ++j) {
        WB1c0[j] = f2bfs(Wm2L[(kk + j) * 32 + c]);
        WB1c1[j] = f2bfs(Wm2L[(kk + j) * 32 + c + 16]);
        int pk = ((kk + j) & 1) * 16 + ((kk + j) >> 1);   // pi-permuted k for GEMM-2
        WBpc0[j] = f2bfs(Wp1L[pk * 32 + c]);
        WBpc1[j] = f2bfs(Wp1L[pk * 32 + c + 16]);
    }

    // ---- per-dst / per-lane constants ----
    float vha[8], vwr[8];
    {
        const float* haR = R + OFF_HA + dstNode * 32 + kk;
        const float* wrR = W_msg1 + layer * 97 * 32 + 64 * 32 + kk;
#pragma unroll
        for (int j = 0; j < 8; ++j) { vha[j] = haR[j]; vwr[j] = wrR[j]; }
    }
    const float vwatt0 = W_att[layer * 32 + c], vwatt1 = W_att[layer * 32 + c + 16];
    const float batt   = b_att[layer];
    const float vbm20  = b_msg2[layer * 32 + c], vbm21 = b_msg2[layer * 32 + c + 16];
    const float vbp10  = b_pos1[layer * 32 + c], vbp11 = b_pos1[layer * 32 + c + 16];
    const float vwp20  = W_pos2[layer * 32 + c], vwp21 = W_pos2[layer * 32 + c + 16];
    const float bp2    = b_pos2[layer];
    const float pxd = R[OFF_P + dstNode * 2], pyd = R[OFF_P + dstNode * 2 + 1];

    unsigned int* mb = mbuf + w * 64 * 20;

    float aghc0 = 0.f, aghc1 = 0.f, apx = 0.f, apy = 0.f, spnx = 0.f, spny = 0.f;

#pragma unroll 1
    for (int half = 0; half < 2; ++half) {
        // ---- phase 0: per-src geometry (lane = src within half) ----
        const int src = (half << 6) + lane;
        const float dx = pxd - sPx[src];
        const float dy = pyd - sPy[src];
        const float radial = dx * dx + dy * dy;
        const float inv = __builtin_amdgcn_rcpf(__builtin_amdgcn_sqrtf(radial) + 1e-6f);
        const float pnx = dx * inv, pny = dy * inv;
        spnx += pnx; spny += pny;

        // ---- phase 1: build m1 A-frags in place, GEMM-1 ----
        f32x4 acc0[4], acc1[4];
#pragma unroll
        for (int tt = 0; tt < 4; ++tt) {
            acc0[tt] = (f32x4){vbm20, vbm20, vbm20, vbm20};
            acc1[tt] = (f32x4){vbm21, vbm21, vbm21, vbm21};
        }
#pragma unroll
        for (int tt = 0; tt < 4; ++tt) {
            const float rad_t = __shfl(radial, c + (tt << 4));
            uint4 hraw = *(const uint4*)(sHBh + ((half << 6) + c + (tt << 4)) * 40 + kk);
            const unsigned short* hs = (const unsigned short*)&hraw;
            bf16x8 af;
#pragma unroll
            for (int j = 0; j < 8; ++j) {
                float x = vha[j] + bf2f(hs[j]) + rad_t * vwr[j];
                af[j] = f2bfs(fsilu(x));
            }
            acc0[tt] = __builtin_amdgcn_mfma_f32_16x16x32_bf16(af, WB1c0, acc0[tt], 0, 0, 0);
            acc1[tt] = __builtin_amdgcn_mfma_f32_16x16x32_bf16(af, WB1c1, acc1[tt], 0, 0, 0);
        }

        // ---- phase 2: silu, attention gate, agh, stage gated m2 (pi-packed bf16) ----
        float pa[16];
#pragma unroll
        for (int tt = 0; tt < 4; ++tt)
#pragma unroll
            for (int j = 0; j < 4; ++j) {
                float s0 = fsilu(acc0[tt][j]);
                float s1 = fsilu(acc1[tt][j]);
                acc0[tt][j] = s0; acc1[tt][j] = s1;
                pa[tt * 4 + j] = s0 * vwatt0 + s1 * vwatt1;
            }
#pragma unroll
        for (int off = 1; off < 16; off <<= 1)
#pragma unroll
            for (int i = 0; i < 16; ++i) pa[i] += __shfl_xor(pa[i], off);
#pragma unroll
        for (int tt = 0; tt < 4; ++tt)
#pragma unroll
            for (int j = 0; j < 4; ++j) {
                float att = fsigmoid(batt + pa[tt * 4 + j]);
                float g0 = acc0[tt][j] * att, g1 = acc1[tt][j] * att;
                aghc0 += g0; aghc1 += g1;
                unsigned int packed = ((unsigned int)(unsigned short)f2bfs(g1) << 16)
                                    | (unsigned short)f2bfs(g0);
                mb[(tt * 16 + rg * 4 + j) * 20 + c] = packed;
            }

        // ---- phase 3: GEMM-2 (q) from staged A-frags ----
        f32x4 q0[4], q1[4];
#pragma unroll
        for (int tt = 0; tt < 4; ++tt) {
            q0[tt] = (f32x4){vbp10, vbp10, vbp10, vbp10};
            q1[tt] = (f32x4){vbp11, vbp11, vbp11, vbp11};
        }
#pragma unroll
        for (int tt = 0; tt < 4; ++tt) {
            union { uint4 u; bf16x8 v; } qa;
            qa.u = *(const uint4*)(mb + (c + (tt << 4)) * 20 + (rg << 2));
            q0[tt] = __builtin_amdgcn_mfma_f32_16x16x32_bf16(qa.v, WBpc0, q0[tt], 0, 0, 0);
            q1[tt] = __builtin_amdgcn_mfma_f32_16x16x32_bf16(qa.v, WBpc1, q1[tt], 0, 0, 0);
        }

        // ---- phase 4: pw and weighted pd accumulation ----
#pragma unroll
        for (int tt = 0; tt < 4; ++tt)
#pragma unroll
            for (int j = 0; j < 4; ++j) {
                float s = fsilu(q0[tt][j]) * vwp20 + fsilu(q1[tt][j]) * vwp21;
                int r = tt * 16 + rg * 4 + j;
                apx += s * __shfl(pnx, r);
                apy += s * __shfl(pny, r);
            }
    }

    // ---- epilogue: reductions + stores ----
    aghc0 += __shfl_xor(aghc0, 16); aghc0 += __shfl_xor(aghc0, 32);
    aghc1 += __shfl_xor(aghc1, 16); aghc1 += __shfl_xor(aghc1, 32);
#pragma unroll
    for (int off = 1; off < 64; off <<= 1) {
        apx  += __shfl_xor(apx, off);
        apy  += __shfl_xor(apy, off);
        spnx += __shfl_xor(spnx, off);
        spny += __shfl_xor(spny, off);
    }
    if (lane < 16)       aggh[dstNode * 32 + lane] = aghc0;
    else if (lane < 32)  aggh[dstNode * 32 + lane] = aghc1;
    if (lane == 0) {
        aggp[dstNode * 2]     = (apx + bp2 * spnx) * (1.0f / 128.0f);
        aggp[dstNode * 2 + 1] = (apy + bp2 * spny) * (1.0f / 128.0f);
    }
}

// ---------------- node update, pre-kernel style: thread = (node, channel) ----------------
// 1024 blocks x 256 thr; block handles 8 nodes. LDS round-trip for the u1->u2 dep.
__global__ __launch_bounds__(256) void node_kernel(
    float* __restrict__ ws,
    const float* __restrict__ W_node1, const float* __restrict__ b_node1,
    const float* __restrict__ W_node2, const float* __restrict__ b_node2,
    const float* __restrict__ W_t, const float* __restrict__ b_t,
    int layer)
{
    __shared__ float sIn[8][64];    // h (0..31) | aggh (32..63) per local node
    __shared__ float sU1[8][32];

    const int tid = blockIdx.x * 256 + threadIdx.x;   // (node, c)
    const int c = tid & 31;
    const int node = tid >> 5;
    const int ln = (threadIdx.x >> 5) & 7;

    const float* __restrict__ Wn1 = W_node1 + layer * 2048;
    const float* __restrict__ Wn2 = W_node2 + layer * 1024;

    sIn[ln][c]      = ws[OFF_H + node * 32 + c];
    sIn[ln][32 + c] = ws[OFF_AGH + node * 32 + c];
    __syncthreads();

    float acc = b_node1[layer * 32 + c];
#pragma unroll
    for (int k = 0; k < 32; ++k)
        acc += sIn[ln][k] * Wn1[k * 32 + c] + sIn[ln][32 + k] * Wn1[(32 + k) * 32 + c];
    sU1[ln][c] = fsilu(acc);
    __syncthreads();

    float u = b_node2[layer * 32 + c];
#pragma unroll
    for (int k = 0; k < 32; ++k) u += sU1[ln][k] * Wn2[k * 32 + c];
    const float hn = (u > 0.f ? u : 0.01f * u) + sIn[ln][c];
    ws[OFF_H + node * 32 + c] = hn;

    if (c < 2)                                       // p += aggr_p (2 lanes per node)
        ws[OFF_P + node * 2 + c] += ws[OFF_AGP + node * 2 + c];

    if (tid < B * 32) {                              // temb update (double-buffered)
        const int g = tid >> 5, c2 = tid & 31;
        const float* Wt = W_t + layer * 1024;
        const float* tin = ws + ((layer & 1) ? OFF_TEMB1 : OFF_TEMB0) + g * 32;
        float acc2 = b_t[layer * 32 + c2];
#pragma unroll
        for (int k = 0; k < 32; ++k) acc2 += tin[k] * Wt[k * 32 + c2];
        ws[((layer & 1) ? OFF_TEMB0 : OFF_TEMB1) + tid] = fsilu(acc2);
    }
}

// ---------------- final: p += aggr_p for shelves, emit fp32 ----------------
__global__ __launch_bounds__(256) void out_kernel(const float* __restrict__ R,
                                                  float* __restrict__ out)
{
    const int o = blockIdx.x * 256 + threadIdx.x;     // 0..14335
    if (o >= B * NSH * 2) return;
    const int d = o & 1;
    const int s = (o >> 1) % NSH;
    const int b = (o >> 1) / NSH;
    const int node = b * 128 + NG + s;
    out[o] = R[OFF_P + node * 2 + d] + R[OFF_AGP + node * 2 + d];
}

// ---------------- launch ----------------
extern "C" void kernel_launch(void* const* d_in, const int* in_sizes, int n_in,
                              void* d_out, int out_size, void* d_ws, size_t ws_size,
                              hipStream_t stream)
{
    const float* pos      = (const float*)d_in[0];
    const int*   tsteps   = (const int*)d_in[1];
    const float* goal_pos = (const float*)d_in[2];
    const float* W_hin    = (const float*)d_in[3];
    const float* b_hin    = (const float*)d_in[4];
    const float* W_msg1   = (const float*)d_in[5];
    const float* b_msg1   = (const float*)d_in[6];
    const float* W_msg2   = (const float*)d_in[7];
    const float* b_msg2   = (const float*)d_in[8];
    const float* W_att    = (const float*)d_in[9];
    const float* b_att    = (const float*)d_in[10];
    const float* W_pos1   = (const float*)d_in[11];
    const float* b_pos1   = (const float*)d_in[12];
    const float* W_pos2   = (const float*)d_in[13];
    const float* b_pos2   = (const float*)d_in[14];
    const float* W_node1  = (const float*)d_in[15];
    const float* b_node1  = (const float*)d_in[16];
    const float* W_node2  = (const float*)d_in[17];
    const float* b_node2  = (const float*)d_in[18];
    const float* W_t      = (const float*)d_in[19];
    const float* b_t      = (const float*)d_in[20];

    float* ws = (float*)d_ws;

    constexpr int setup_threads = NN * 32 + NN * 2 + B * 32;
    setup_kernel<<<(setup_threads + 255) / 256, 256, 0, stream>>>(
        pos, tsteps, goal_pos, W_hin, b_hin, ws);

    for (int l = 0; l < L; ++l) {
        const float* tembIn = ws + ((l & 1) ? OFF_TEMB1 : OFF_TEMB0);
        pre_kernel<<<NN * 32 / 256, 256, 0, stream>>>(ws, W_msg1, b_msg1, tembIn, l);
        edge_kernel<<<2048, 256, 0, stream>>>(ws, W_msg1, W_msg2, b_msg2, W_att, b_att,
                                              W_pos1, b_pos1, W_pos2, b_pos2,
                                              ws + OFF_AGH, ws + OFF_AGP, l);
        if (l < L - 1)
            node_kernel<<<NN * 32 / 256, 256, 0, stream>>>(ws, W_node1, b_node1, W_node2,
                                                           b_node2, W_t, b_t, l);
    }
    out_kernel<<<(B * NSH * 2 + 255) / 256, 256, 0, stream>>>(ws, (float*)d_out);
}

// Round 5
// 350.885 us; speedup vs baseline: 3.6099x; 1.0504x over previous
//
#include <hip/hip_runtime.h>
#include <hip/hip_bf16.h>

// ---------------- problem constants ----------------
constexpr int B = 64;
constexpr int NG = 16;
constexpr int NSH = 112;
constexpr int N = 128;          // nodes per graph
constexpr int NN = B * N;       // 8192 total nodes
constexpr int L = 5;

// ---------------- workspace layout (float offsets) ----------------
constexpr int OFF_H     = 0;                    // [8192][32] f32
constexpr int OFF_P     = OFF_H + NN * 32;      // [8192][2]  f32
constexpr int OFF_TEMB0 = OFF_P + NN * 2;       // [64][32]
constexpr int OFF_TEMB1 = OFF_TEMB0 + B * 32;
constexpr int OFF_HA    = OFF_TEMB1 + B * 32;   // [8192][32] f32 (h[dst]-term + temb-term + b_msg1)
constexpr int OFF_HB    = OFF_HA + NN * 32;     // [8192][32] stored as ushort bf16 (h[src]-term)
constexpr int OFF_AGH   = OFF_HB + NN * 32;     // [8192][32] f32
constexpr int OFF_AGP   = OFF_AGH + NN * 32;    // [8192][2]  f32

typedef __attribute__((ext_vector_type(8))) short bf16x8;
typedef __attribute__((ext_vector_type(4))) float f32x4;

// ---------------- math helpers ----------------
__device__ __forceinline__ float fsigmoid(float x) {
    return __builtin_amdgcn_rcpf(1.0f + __expf(-x));
}
__device__ __forceinline__ float fsilu(float x) { return x * fsigmoid(x); }
__device__ __forceinline__ short f2bfs(float f) {
    union { __hip_bfloat16 b; short s; } u; u.b = __float2bfloat16(f); return u.s;
}
__device__ __forceinline__ float bf2f(unsigned short u) {
    union { unsigned int i; float f; } v; v.i = ((unsigned int)u) << 16; return v.f;
}

// ---------------- setup: init h / p / temb0 ----------------
__global__ __launch_bounds__(256) void setup_kernel(
    const float* __restrict__ pos, const int* __restrict__ timesteps,
    const float* __restrict__ goal_pos,
    const float* __restrict__ W_hin, const float* __restrict__ b_hin,
    float* __restrict__ ws)
{
    int idx = blockIdx.x * 256 + threadIdx.x;

    if (idx < NN * 32) {                       // h init: goals use W_hin row 0, shelves row 1
        int c = idx & 31; int node = idx >> 5; int local = node & 127;
        int row = (local < NG) ? 0 : 1;
        ws[OFF_H + idx] = W_hin[row * 32 + c] + b_hin[c];
        return;
    }
    idx -= NN * 32;
    if (idx < NN * 2) {                        // p init
        int d = idx & 1; int node = idx >> 1; int g = node >> 7; int local = node & 127;
        float v = (local < NG) ? goal_pos[local * 2 + d]
                               : pos[(g * NSH + (local - NG)) * 2 + d];
        ws[OFF_P + idx] = v;
        return;
    }
    idx -= NN * 2;
    if (idx < B * 32) {                        // sinusoidal timestep embedding
        int j = idx & 31; int g = idx >> 5;
        float t = (float)timesteps[g];
        int jj = (j < 16) ? j : (j - 16);
        float freq = expf(-logf(10000.0f) * (float)jj / 16.0f);
        float ang = t * freq;
        ws[OFF_TEMB0 + idx] = (j < 16) ? cosf(ang) : sinf(ang);
    }
}

// ---------------- per-layer node precompute: HA (f32), HBh (bf16) ----------------
__global__ __launch_bounds__(256) void pre_kernel(
    float* __restrict__ R,
    const float* __restrict__ W_msg1, const float* __restrict__ b_msg1,
    const float* __restrict__ tembIn, int layer)
{
    int tid = blockIdx.x * 256 + threadIdx.x;   // 0 .. 262143
    int c = tid & 31; int node = tid >> 5; int g = node >> 7;
    const float* __restrict__ W1 = W_msg1 + layer * 97 * 32;
    float accA = b_msg1[layer * 32 + c];
    float accB = 0.f;
#pragma unroll
    for (int k = 0; k < 32; ++k) {
        float hk = R[OFF_H + node * 32 + k];
        accA += hk * W1[k * 32 + c];
        accB += hk * W1[(32 + k) * 32 + c];
    }
#pragma unroll
    for (int k = 0; k < 32; ++k)
        accA += tembIn[g * 32 + k] * W1[(65 + k) * 32 + c];
    R[OFF_HA + tid] = accA;
    ((unsigned short*)(R + OFF_HB))[tid] = (unsigned short)f2bfs(accB);
}

// ---------------- edge kernel (MFMA): messages + gated aggregation ----------------
// grid: 64 graphs x 32 dst-groups = 2048 blocks, 256 thr = 4 waves.
// att gate commutes through GEMM-2 (per-row scalar); attz computed via MFMA
// with column-replicated W_att B-fragment -> no cross-lane butterflies.
__global__ __launch_bounds__(256, 4) void edge_kernel(
    float* __restrict__ R,
    const float* __restrict__ W_msg1,
    const float* __restrict__ W_msg2, const float* __restrict__ b_msg2,
    const float* __restrict__ W_att, const float* __restrict__ b_att,
    const float* __restrict__ W_pos1, const float* __restrict__ b_pos1,
    const float* __restrict__ W_pos2, const float* __restrict__ b_pos2,
    float* __restrict__ aggh, float* __restrict__ aggp, int layer)
{
    __shared__ unsigned short sHBh[128 * 40];   // bf16, row stride 40 (80B, 16B-aligned)
    __shared__ float sPx[128], sPy[128];
    __shared__ unsigned int mbuf[4 * 64 * 20];  // per-wave s-staging (pi-packed bf16 pairs)
    __shared__ float2 spn[4][64];               // per-wave (pnx,pny) row-broadcast buffer

    const int t = threadIdx.x;
    const int bx = blockIdx.x;
    const int g = bx >> 5;
    const int gbase = g * 128;

    // ---- stage HBh (graph's 128x32 bf16) + positions ----
    const unsigned short* HBH = (const unsigned short*)(R + OFF_HB);
#pragma unroll
    for (int ch = 0; ch < 2; ++ch) {
        int chunk = t + ch * 256;               // 512 chunks of 8 bf16
        int row = chunk >> 2, g4 = chunk & 3;
        uint4 v = *(const uint4*)(HBH + (gbase + row) * 32 + (g4 << 3));
        *(uint4*)(sHBh + row * 40 + (g4 << 3)) = v;
    }
    if (t < 128) {
        sPx[t] = R[OFF_P + (gbase + t) * 2];
        sPy[t] = R[OFF_P + (gbase + t) * 2 + 1];
    }
    __syncthreads();

    const int lane = t & 63, w = t >> 6;
    const int c = lane & 15;
    const int rg = lane >> 4;
    const int kk = rg << 3;
    const int dloc = ((bx & 31) << 2) | w;
    const int dstNode = gbase + dloc;

    // ---- resident weight fragments (bf16) ----
    const float* __restrict__ Wm2L = W_msg2 + layer * 1024;
    const float* __restrict__ Wp1L = W_pos1 + layer * 1024;
    bf16x8 WB1c0, WB1c1, WBpc0, WBpc1, WBac;
#pragma unroll
    for (int j = 0; j < 8; ++j) {
        WB1c0[j] = f2bfs(Wm2L[(kk + j) * 32 + c]);
        WB1c1[j] = f2bfs(Wm2L[(kk + j) * 32 + c + 16]);
        int pk = ((kk + j) & 1) * 16 + ((kk + j) >> 1);   // pi-permuted k for staged A
        WBpc0[j] = f2bfs(Wp1L[pk * 32 + c]);
        WBpc1[j] = f2bfs(Wp1L[pk * 32 + c + 16]);
        WBac[j]  = f2bfs(W_att[layer * 32 + pk]);         // column-replicated
    }

    // ---- per-dst / per-lane constants ----
    float vha[8], vwr[8];
    {
        const float* haR = R + OFF_HA + dstNode * 32 + kk;
        const float* wrR = W_msg1 + layer * 97 * 32 + 64 * 32 + kk;
#pragma unroll
        for (int j = 0; j < 8; ++j) { vha[j] = haR[j]; vwr[j] = wrR[j]; }
    }
    const float batt   = b_att[layer];
    const float vbm20  = b_msg2[layer * 32 + c], vbm21 = b_msg2[layer * 32 + c + 16];
    const float vbp10  = b_pos1[layer * 32 + c], vbp11 = b_pos1[layer * 32 + c + 16];
    const float vwp20  = W_pos2[layer * 32 + c], vwp21 = W_pos2[layer * 32 + c + 16];
    const float bp2    = b_pos2[layer];
    const float pxd = R[OFF_P + dstNode * 2], pyd = R[OFF_P + dstNode * 2 + 1];

    unsigned int* mb = mbuf + w * 64 * 20;

    float aghc0 = 0.f, aghc1 = 0.f, apx = 0.f, apy = 0.f, spnx = 0.f, spny = 0.f;

#pragma unroll 1
    for (int half = 0; half < 2; ++half) {
        // ---- phase 0: per-src geometry (lane = src within half) ----
        const int src = (half << 6) + lane;
        const float dx = pxd - sPx[src];
        const float dy = pyd - sPy[src];
        const float radial = dx * dx + dy * dy;
        const float inv = __builtin_amdgcn_rcpf(__builtin_amdgcn_sqrtf(radial) + 1e-6f);
        const float pnx = dx * inv, pny = dy * inv;
        spnx += pnx; spny += pny;
        spn[w][lane] = (float2){pnx, pny};

        // ---- phase 1: build m1 A-frags in place, GEMM-1 ----
        f32x4 acc0[4], acc1[4];
#pragma unroll
        for (int tt = 0; tt < 4; ++tt) {
            acc0[tt] = (f32x4){vbm20, vbm20, vbm20, vbm20};
            acc1[tt] = (f32x4){vbm21, vbm21, vbm21, vbm21};
        }
#pragma unroll
        for (int tt = 0; tt < 4; ++tt) {
            const float rad_t = __shfl(radial, c + (tt << 4));
            uint4 hraw = *(const uint4*)(sHBh + ((half << 6) + c + (tt << 4)) * 40 + kk);
            const unsigned short* hs = (const unsigned short*)&hraw;
            bf16x8 af;
#pragma unroll
            for (int j = 0; j < 8; ++j) {
                float x = vha[j] + bf2f(hs[j]) + rad_t * vwr[j];
                af[j] = f2bfs(fsilu(x));
            }
            acc0[tt] = __builtin_amdgcn_mfma_f32_16x16x32_bf16(af, WB1c0, acc0[tt], 0, 0, 0);
            acc1[tt] = __builtin_amdgcn_mfma_f32_16x16x32_bf16(af, WB1c1, acc1[tt], 0, 0, 0);
        }

        // ---- phase 2: silu, stage UNGATED s (pi-packed bf16 pairs) ----
#pragma unroll
        for (int tt = 0; tt < 4; ++tt)
#pragma unroll
            for (int j = 0; j < 4; ++j) {
                float s0 = fsilu(acc0[tt][j]);
                float s1 = fsilu(acc1[tt][j]);
                acc0[tt][j] = s0; acc1[tt][j] = s1;
                unsigned int packed = ((unsigned int)(unsigned short)f2bfs(s1) << 16)
                                    | (unsigned short)f2bfs(s0);
                mb[(tt * 16 + rg * 4 + j) * 20 + c] = packed;
            }

        // ---- phase 3: per tile: attz MFMA + z MFMAs, then gate/pw/aggregate ----
#pragma unroll
        for (int tt = 0; tt < 4; ++tt) {
            union { uint4 u; bf16x8 v; } qa;
            qa.u = *(const uint4*)(mb + (c + (tt << 4)) * 20 + (rg << 2));
            f32x4 za = (f32x4){batt, batt, batt, batt};
            f32x4 z0 = (f32x4){0.f, 0.f, 0.f, 0.f};
            f32x4 z1 = (f32x4){0.f, 0.f, 0.f, 0.f};
            za = __builtin_amdgcn_mfma_f32_16x16x32_bf16(qa.v, WBac,  za, 0, 0, 0);
            z0 = __builtin_amdgcn_mfma_f32_16x16x32_bf16(qa.v, WBpc0, z0, 0, 0, 0);
            z1 = __builtin_amdgcn_mfma_f32_16x16x32_bf16(qa.v, WBpc1, z1, 0, 0, 0);
#pragma unroll
            for (int j = 0; j < 4; ++j) {
                const float att = fsigmoid(za[j]);
                aghc0 += att * acc0[tt][j];
                aghc1 += att * acc1[tt][j];
                const float q0 = fsilu(att * z0[j] + vbp10);
                const float q1 = fsilu(att * z1[j] + vbp11);
                const float pwp = q0 * vwp20 + q1 * vwp21;
                const float2 pn = spn[w][(tt << 4) + (rg << 2) + j];
                apx += pwp * pn.x;
                apy += pwp * pn.y;
            }
        }
    }

    // ---- epilogue: reductions + stores ----
    aghc0 += __shfl_xor(aghc0, 16); aghc0 += __shfl_xor(aghc0, 32);
    aghc1 += __shfl_xor(aghc1, 16); aghc1 += __shfl_xor(aghc1, 32);
#pragma unroll
    for (int off = 1; off < 64; off <<= 1) {
        apx  += __shfl_xor(apx, off);
        apy  += __shfl_xor(apy, off);
        spnx += __shfl_xor(spnx, off);
        spny += __shfl_xor(spny, off);
    }
    if (lane < 16)       aggh[dstNode * 32 + lane] = aghc0;
    else if (lane < 32)  aggh[dstNode * 32 + lane] = aghc1;
    if (lane == 0) {
        aggp[dstNode * 2]     = (apx + bp2 * spnx) * (1.0f / 128.0f);
        aggp[dstNode * 2 + 1] = (apy + bp2 * spny) * (1.0f / 128.0f);
    }
}

// ---------------- node update, thread = (node, channel) ----------------
__global__ __launch_bounds__(256) void node_kernel(
    float* __restrict__ ws,
    const float* __restrict__ W_node1, const float* __restrict__ b_node1,
    const float* __restrict__ W_node2, const float* __restrict__ b_node2,
    const float* __restrict__ W_t, const float* __restrict__ b_t,
    int layer)
{
    __shared__ float sIn[8][64];    // h (0..31) | aggh (32..63) per local node
    __shared__ float sU1[8][32];

    const int tid = blockIdx.x * 256 + threadIdx.x;   // (node, c)
    const int c = tid & 31;
    const int node = tid >> 5;
    const int ln = (threadIdx.x >> 5) & 7;

    const float* __restrict__ Wn1 = W_node1 + layer * 2048;
    const float* __restrict__ Wn2 = W_node2 + layer * 1024;

    sIn[ln][c]      = ws[OFF_H + node * 32 + c];
    sIn[ln][32 + c] = ws[OFF_AGH + node * 32 + c];
    __syncthreads();

    float acc = b_node1[layer * 32 + c];
#pragma unroll
    for (int k = 0; k < 32; ++k)
        acc += sIn[ln][k] * Wn1[k * 32 + c] + sIn[ln][32 + k] * Wn1[(32 + k) * 32 + c];
    sU1[ln][c] = fsilu(acc);
    __syncthreads();

    float u = b_node2[layer * 32 + c];
#pragma unroll
    for (int k = 0; k < 32; ++k) u += sU1[ln][k] * Wn2[k * 32 + c];
    const float hn = (u > 0.f ? u : 0.01f * u) + sIn[ln][c];
    ws[OFF_H + node * 32 + c] = hn;

    if (c < 2)                                       // p += aggr_p (2 lanes per node)
        ws[OFF_P + node * 2 + c] += ws[OFF_AGP + node * 2 + c];

    if (tid < B * 32) {                              // temb update (double-buffered)
        const int g = tid >> 5, c2 = tid & 31;
        const float* Wt = W_t + layer * 1024;
        const float* tin = ws + ((layer & 1) ? OFF_TEMB1 : OFF_TEMB0) + g * 32;
        float acc2 = b_t[layer * 32 + c2];
#pragma unroll
        for (int k = 0; k < 32; ++k) acc2 += tin[k] * Wt[k * 32 + c2];
        ws[((layer & 1) ? OFF_TEMB0 : OFF_TEMB1) + tid] = fsilu(acc2);
    }
}

// ---------------- final: p += aggr_p for shelves, emit fp32 ----------------
__global__ __launch_bounds__(256) void out_kernel(const float* __restrict__ R,
                                                  float* __restrict__ out)
{
    const int o = blockIdx.x * 256 + threadIdx.x;     // 0..14335
    if (o >= B * NSH * 2) return;
    const int d = o & 1;
    const int s = (o >> 1) % NSH;
    const int b = (o >> 1) / NSH;
    const int node = b * 128 + NG + s;
    out[o] = R[OFF_P + node * 2 + d] + R[OFF_AGP + node * 2 + d];
}

// ---------------- launch ----------------
extern "C" void kernel_launch(void* const* d_in, const int* in_sizes, int n_in,
                              void* d_out, int out_size, void* d_ws, size_t ws_size,
                              hipStream_t stream)
{
    const float* pos      = (const float*)d_in[0];
    const int*   tsteps   = (const int*)d_in[1];
    const float* goal_pos = (const float*)d_in[2];
    const float* W_hin    = (const float*)d_in[3];
    const float* b_hin    = (const float*)d_in[4];
    const float* W_msg1   = (const float*)d_in[5];
    const float* b_msg1   = (const float*)d_in[6];
    const float* W_msg2   = (const float*)d_in[7];
    const float* b_msg2   = (const float*)d_in[8];
    const float* W_att    = (const float*)d_in[9];
    const float* b_att    = (const float*)d_in[10];
    const float* W_pos1   = (const float*)d_in[11];
    const float* b_pos1   = (const float*)d_in[12];
    const float* W_pos2   = (const float*)d_in[13];
    const float* b_pos2   = (const float*)d_in[14];
    const float* W_node1  = (const float*)d_in[15];
    const float* b_node1  = (const float*)d_in[16];
    const float* W_node2  = (const float*)d_in[17];
    const float* b_node2  = (const float*)d_in[18];
    const float* W_t      = (const float*)d_in[19];
    const float* b_t      = (const float*)d_in[20];

    float* ws = (float*)d_ws;

    constexpr int setup_threads = NN * 32 + NN * 2 + B * 32;
    setup_kernel<<<(setup_threads + 255) / 256, 256, 0, stream>>>(
        pos, tsteps, goal_pos, W_hin, b_hin, ws);

    for (int l = 0; l < L; ++l) {
        const float* tembIn = ws + ((l & 1) ? OFF_TEMB1 : OFF_TEMB0);
        pre_kernel<<<NN * 32 / 256, 256, 0, stream>>>(ws, W_msg1, b_msg1, tembIn, l);
        edge_kernel<<<2048, 256, 0, stream>>>(ws, W_msg1, W_msg2, b_msg2, W_att, b_att,
                                              W_pos1, b_pos1, W_pos2, b_pos2,
                                              ws + OFF_AGH, ws + OFF_AGP, l);
        if (l < L - 1)
            node_kernel<<<NN * 32 / 256, 256, 0, stream>>>(ws, W_node1, b_node1, W_node2,
                                                           b_node2, W_t, b_t, l);
    }
    out_kernel<<<(B * NSH * 2 + 255) / 256, 256, 0, stream>>>(ws, (float*)d_out);
}

// Round 6
// 324.912 us; speedup vs baseline: 3.8985x; 1.0799x over previous
//
#include <hip/hip_runtime.h>
#include <hip/hip_bf16.h>

// ---------------- problem constants ----------------
constexpr int B = 64;
constexpr int NG = 16;
constexpr int NSH = 112;
constexpr int N = 128;          // nodes per graph
constexpr int NN = B * N;       // 8192 total nodes
constexpr int L = 5;

// ---------------- workspace layout (float offsets) ----------------
constexpr int OFF_H     = 0;                    // [8192][32] f32
constexpr int OFF_P     = OFF_H + NN * 32;      // [8192][2]  f32
constexpr int OFF_TEMB0 = OFF_P + NN * 2;       // [64][32]
constexpr int OFF_TEMB1 = OFF_TEMB0 + B * 32;
constexpr int OFF_HA    = OFF_TEMB1 + B * 32;   // [8192][32] f32 (h[dst]-term + temb-term + b_msg1)
constexpr int OFF_HB    = OFF_HA + NN * 32;     // [8192][32] stored as ushort bf16 (h[src]-term)
constexpr int OFF_AGH   = OFF_HB + NN * 32;     // [8192][32] f32
constexpr int OFF_AGP   = OFF_AGH + NN * 32;    // [8192][2]  f32

typedef __attribute__((ext_vector_type(8))) short bf16x8;
typedef __attribute__((ext_vector_type(4))) float f32x4;

// ---------------- math helpers ----------------
__device__ __forceinline__ float fsigmoid(float x) {
    return __builtin_amdgcn_rcpf(1.0f + __expf(-x));
}
__device__ __forceinline__ float fsilu(float x) { return x * fsigmoid(x); }
__device__ __forceinline__ short f2bfs(float f) {           // RNE (setup paths only)
    union { __hip_bfloat16 b; short s; } u; u.b = __float2bfloat16(f); return u.s;
}
__device__ __forceinline__ float bf2f(unsigned short u) {
    union { unsigned int i; float f; } v; v.i = ((unsigned int)u) << 16; return v.f;
}
// single-inst truncation pack: dst = bf16(hi)<<16 | bf16(lo)
__device__ __forceinline__ unsigned int pk_trunc(float lo, float hi) {
    union { float f; unsigned int u; } a, b;
    a.f = hi; b.f = lo;
    return __builtin_amdgcn_perm(a.u, b.u, 0x07060302u);
}

// ---------------- setup: init h / p / temb0 ----------------
__global__ __launch_bounds__(256) void setup_kernel(
    const float* __restrict__ pos, const int* __restrict__ timesteps,
    const float* __restrict__ goal_pos,
    const float* __restrict__ W_hin, const float* __restrict__ b_hin,
    float* __restrict__ ws)
{
    int idx = blockIdx.x * 256 + threadIdx.x;

    if (idx < NN * 32) {                       // h init: goals use W_hin row 0, shelves row 1
        int c = idx & 31; int node = idx >> 5; int local = node & 127;
        int row = (local < NG) ? 0 : 1;
        ws[OFF_H + idx] = W_hin[row * 32 + c] + b_hin[c];
        return;
    }
    idx -= NN * 32;
    if (idx < NN * 2) {                        // p init
        int d = idx & 1; int node = idx >> 1; int g = node >> 7; int local = node & 127;
        float v = (local < NG) ? goal_pos[local * 2 + d]
                               : pos[(g * NSH + (local - NG)) * 2 + d];
        ws[OFF_P + idx] = v;
        return;
    }
    idx -= NN * 2;
    if (idx < B * 32) {                        // sinusoidal timestep embedding
        int j = idx & 31; int g = idx >> 5;
        float t = (float)timesteps[g];
        int jj = (j < 16) ? j : (j - 16);
        float freq = expf(-logf(10000.0f) * (float)jj / 16.0f);
        float ang = t * freq;
        ws[OFF_TEMB0 + idx] = (j < 16) ? cosf(ang) : sinf(ang);
    }
}

// ---------------- per-layer node precompute: HA (f32), HBh (bf16) ----------------
__global__ __launch_bounds__(256) void pre_kernel(
    float* __restrict__ R,
    const float* __restrict__ W_msg1, const float* __restrict__ b_msg1,
    const float* __restrict__ tembIn, int layer)
{
    int tid = blockIdx.x * 256 + threadIdx.x;   // 0 .. 262143
    int c = tid & 31; int node = tid >> 5; int g = node >> 7;
    const float* __restrict__ W1 = W_msg1 + layer * 97 * 32;
    float accA = b_msg1[layer * 32 + c];
    float accB = 0.f;
#pragma unroll
    for (int k = 0; k < 32; ++k) {
        float hk = R[OFF_H + node * 32 + k];
        accA += hk * W1[k * 32 + c];
        accB += hk * W1[(32 + k) * 32 + c];
    }
#pragma unroll
    for (int k = 0; k < 32; ++k)
        accA += tembIn[g * 32 + k] * W1[(65 + k) * 32 + c];
    R[OFF_HA + tid] = accA;
    ((unsigned short*)(R + OFF_HB))[tid] = (unsigned short)f2bfs(accB);
}

// ---------------- edge kernel (MFMA): messages + gated aggregation ----------------
// grid: 64 graphs x 32 dst-groups = 2048 blocks, 256 thr = 4 waves.
// waves_per_eu(2,4): cap target occupancy at 4 waves/EU so the allocator gets
// a >=128-VGPR budget (launch_bounds(256,4) let it target 8 -> 64 VGPR -> spills).
__global__ __attribute__((amdgpu_flat_work_group_size(256, 256)))
__attribute__((amdgpu_waves_per_eu(2, 4))) void edge_kernel(
    float* __restrict__ R,
    const float* __restrict__ W_msg1,
    const float* __restrict__ W_msg2, const float* __restrict__ b_msg2,
    const float* __restrict__ W_att, const float* __restrict__ b_att,
    const float* __restrict__ W_pos1, const float* __restrict__ b_pos1,
    const float* __restrict__ W_pos2, const float* __restrict__ b_pos2,
    float* __restrict__ aggh, float* __restrict__ aggp, int layer)
{
    __shared__ unsigned short sHBh[128 * 40];   // bf16, row stride 40 (80B, 16B-aligned)
    __shared__ float sPx[128], sPy[128];
    __shared__ unsigned int mbuf[4 * 64 * 20];  // per-wave s-staging (pi-packed bf16 pairs)
    __shared__ float2 spn[4][64];               // per-wave (pnx,pny) row-broadcast buffer

    const int t = threadIdx.x;
    const int bx = blockIdx.x;
    const int g = bx >> 5;
    const int gbase = g * 128;

    // ---- stage HBh (graph's 128x32 bf16) + positions ----
    const unsigned short* HBH = (const unsigned short*)(R + OFF_HB);
#pragma unroll
    for (int ch = 0; ch < 2; ++ch) {
        int chunk = t + ch * 256;               // 512 chunks of 8 bf16
        int row = chunk >> 2, g4 = chunk & 3;
        uint4 v = *(const uint4*)(HBH + (gbase + row) * 32 + (g4 << 3));
        *(uint4*)(sHBh + row * 40 + (g4 << 3)) = v;
    }
    if (t < 128) {
        sPx[t] = R[OFF_P + (gbase + t) * 2];
        sPy[t] = R[OFF_P + (gbase + t) * 2 + 1];
    }
    __syncthreads();

    const int lane = t & 63, w = t >> 6;
    const int c = lane & 15;
    const int rg = lane >> 4;
    const int kk = rg << 3;
    const int dloc = ((bx & 31) << 2) | w;
    const int dstNode = gbase + dloc;

    // ---- resident weight fragments (bf16, RNE one-time) ----
    const float* __restrict__ Wm2L = W_msg2 + layer * 1024;
    const float* __restrict__ Wp1L = W_pos1 + layer * 1024;
    bf16x8 WB1c0, WB1c1, WBpc0, WBpc1, WBac;
#pragma unroll
    for (int j = 0; j < 8; ++j) {
        WB1c0[j] = f2bfs(Wm2L[(kk + j) * 32 + c]);
        WB1c1[j] = f2bfs(Wm2L[(kk + j) * 32 + c + 16]);
        int pk = ((kk + j) & 1) * 16 + ((kk + j) >> 1);   // pi-permuted k for staged A
        WBpc0[j] = f2bfs(Wp1L[pk * 32 + c]);
        WBpc1[j] = f2bfs(Wp1L[pk * 32 + c + 16]);
        WBac[j]  = f2bfs(W_att[layer * 32 + pk]);         // column-replicated
    }

    // ---- per-dst / per-lane constants ----
    float vha[8], vwr[8];
    {
        const float* haR = R + OFF_HA + dstNode * 32 + kk;
        const float* wrR = W_msg1 + layer * 97 * 32 + 64 * 32 + kk;
#pragma unroll
        for (int j = 0; j < 8; ++j) { vha[j] = haR[j]; vwr[j] = wrR[j]; }
    }
    const float batt   = b_att[layer];
    const float vbm20  = b_msg2[layer * 32 + c], vbm21 = b_msg2[layer * 32 + c + 16];
    const float vbp10  = b_pos1[layer * 32 + c], vbp11 = b_pos1[layer * 32 + c + 16];
    const float vwp20  = W_pos2[layer * 32 + c], vwp21 = W_pos2[layer * 32 + c + 16];
    const float bp2    = b_pos2[layer];
    const float pxd = R[OFF_P + dstNode * 2], pyd = R[OFF_P + dstNode * 2 + 1];

    unsigned int* mb = mbuf + w * 64 * 20;

    float aghc0 = 0.f, aghc1 = 0.f, apx = 0.f, apy = 0.f, spnx = 0.f, spny = 0.f;

#pragma unroll 1
    for (int half = 0; half < 2; ++half) {
        // ---- phase 0: per-src geometry (lane = src within half) ----
        const int src = (half << 6) + lane;
        const float dx = pxd - sPx[src];
        const float dy = pyd - sPy[src];
        const float radial = dx * dx + dy * dy;
        const float inv = __builtin_amdgcn_rcpf(__builtin_amdgcn_sqrtf(radial) + 1e-6f);
        const float pnx = dx * inv, pny = dy * inv;
        spnx += pnx; spny += pny;
        spn[w][lane] = (float2){pnx, pny};

        // ---- phase 1: build m1 A-frags (trunc pack), GEMM-1 ----
        f32x4 acc0[4], acc1[4];
#pragma unroll
        for (int tt = 0; tt < 4; ++tt) {
            acc0[tt] = (f32x4){vbm20, vbm20, vbm20, vbm20};
            acc1[tt] = (f32x4){vbm21, vbm21, vbm21, vbm21};
        }
#pragma unroll
        for (int tt = 0; tt < 4; ++tt) {
            const float rad_t = __shfl(radial, c + (tt << 4));
            uint4 hraw = *(const uint4*)(sHBh + ((half << 6) + c + (tt << 4)) * 40 + kk);
            const unsigned short* hs = (const unsigned short*)&hraw;
            float x[8];
#pragma unroll
            for (int j = 0; j < 8; ++j)
                x[j] = fsilu(vha[j] + bf2f(hs[j]) + rad_t * vwr[j]);
            union { unsigned int u[4]; bf16x8 v; } af;
#pragma unroll
            for (int d = 0; d < 4; ++d) af.u[d] = pk_trunc(x[2 * d], x[2 * d + 1]);
            acc0[tt] = __builtin_amdgcn_mfma_f32_16x16x32_bf16(af.v, WB1c0, acc0[tt], 0, 0, 0);
            acc1[tt] = __builtin_amdgcn_mfma_f32_16x16x32_bf16(af.v, WB1c1, acc1[tt], 0, 0, 0);
        }

        // ---- phase 2: silu, stage UNGATED s (pi-packed bf16 pairs, trunc) ----
#pragma unroll
        for (int tt = 0; tt < 4; ++tt)
#pragma unroll
            for (int j = 0; j < 4; ++j) {
                float s0 = fsilu(acc0[tt][j]);
                float s1 = fsilu(acc1[tt][j]);
                acc0[tt][j] = s0; acc1[tt][j] = s1;
                mb[(tt * 16 + rg * 4 + j) * 20 + c] = pk_trunc(s0, s1);
            }

        // ---- phase 3: per tile: attz MFMA + z MFMAs, then gate/pw/aggregate ----
#pragma unroll
        for (int tt = 0; tt < 4; ++tt) {
            union { uint4 u; bf16x8 v; } qa;
            qa.u = *(const uint4*)(mb + (c + (tt << 4)) * 20 + (rg << 2));
            f32x4 za = (f32x4){batt, batt, batt, batt};
            f32x4 z0 = (f32x4){0.f, 0.f, 0.f, 0.f};
            f32x4 z1 = (f32x4){0.f, 0.f, 0.f, 0.f};
            za = __builtin_amdgcn_mfma_f32_16x16x32_bf16(qa.v, WBac,  za, 0, 0, 0);
            z0 = __builtin_amdgcn_mfma_f32_16x16x32_bf16(qa.v, WBpc0, z0, 0, 0, 0);
            z1 = __builtin_amdgcn_mfma_f32_16x16x32_bf16(qa.v, WBpc1, z1, 0, 0, 0);
#pragma unroll
            for (int j = 0; j < 4; ++j) {
                const float att = fsigmoid(za[j]);
                aghc0 += att * acc0[tt][j];
                aghc1 += att * acc1[tt][j];
                const float q0 = fsilu(att * z0[j] + vbp10);
                const float q1 = fsilu(att * z1[j] + vbp11);
                const float pwp = q0 * vwp20 + q1 * vwp21;
                const float2 pn = spn[w][(tt << 4) + (rg << 2) + j];
                apx += pwp * pn.x;
                apy += pwp * pn.y;
            }
        }
    }

    // ---- epilogue: reductions + stores ----
    aghc0 += __shfl_xor(aghc0, 16); aghc0 += __shfl_xor(aghc0, 32);
    aghc1 += __shfl_xor(aghc1, 16); aghc1 += __shfl_xor(aghc1, 32);
#pragma unroll
    for (int off = 1; off < 64; off <<= 1) {
        apx  += __shfl_xor(apx, off);
        apy  += __shfl_xor(apy, off);
        spnx += __shfl_xor(spnx, off);
        spny += __shfl_xor(spny, off);
    }
    if (lane < 16)       aggh[dstNode * 32 + lane] = aghc0;
    else if (lane < 32)  aggh[dstNode * 32 + lane] = aghc1;
    if (lane == 0) {
        aggp[dstNode * 2]     = (apx + bp2 * spnx) * (1.0f / 128.0f);
        aggp[dstNode * 2 + 1] = (apy + bp2 * spny) * (1.0f / 128.0f);
    }
}

// ---------------- node update, thread = (node, channel) ----------------
__global__ __launch_bounds__(256) void node_kernel(
    float* __restrict__ ws,
    const float* __restrict__ W_node1, const float* __restrict__ b_node1,
    const float* __restrict__ W_node2, const float* __restrict__ b_node2,
    const float* __restrict__ W_t, const float* __restrict__ b_t,
    int layer)
{
    __shared__ float sIn[8][64];    // h (0..31) | aggh (32..63) per local node
    __shared__ float sU1[8][32];

    const int tid = blockIdx.x * 256 + threadIdx.x;   // (node, c)
    const int c = tid & 31;
    const int node = tid >> 5;
    const int ln = (threadIdx.x >> 5) & 7;

    const float* __restrict__ Wn1 = W_node1 + layer * 2048;
    const float* __restrict__ Wn2 = W_node2 + layer * 1024;

    sIn[ln][c]      = ws[OFF_H + node * 32 + c];
    sIn[ln][32 + c] = ws[OFF_AGH + node * 32 + c];
    __syncthreads();

    float acc = b_node1[layer * 32 + c];
#pragma unroll
    for (int k = 0; k < 32; ++k)
        acc += sIn[ln][k] * Wn1[k * 32 + c] + sIn[ln][32 + k] * Wn1[(32 + k) * 32 + c];
    sU1[ln][c] = fsilu(acc);
    __syncthreads();

    float u = b_node2[layer * 32 + c];
#pragma unroll
    for (int k = 0; k < 32; ++k) u += sU1[ln][k] * Wn2[k * 32 + c];
    const float hn = (u > 0.f ? u : 0.01f * u) + sIn[ln][c];
    ws[OFF_H + node * 32 + c] = hn;

    if (c < 2)                                       // p += aggr_p (2 lanes per node)
        ws[OFF_P + node * 2 + c] += ws[OFF_AGP + node * 2 + c];

    if (tid < B * 32) {                              // temb update (double-buffered)
        const int g = tid >> 5, c2 = tid & 31;
        const float* Wt = W_t + layer * 1024;
        const float* tin = ws + ((layer & 1) ? OFF_TEMB1 : OFF_TEMB0) + g * 32;
        float acc2 = b_t[layer * 32 + c2];
#pragma unroll
        for (int k = 0; k < 32; ++k) acc2 += tin[k] * Wt[k * 32 + c2];
        ws[((layer & 1) ? OFF_TEMB0 : OFF_TEMB1) + tid] = fsilu(acc2);
    }
}

// ---------------- final: p += aggr_p for shelves, emit fp32 ----------------
__global__ __launch_bounds__(256) void out_kernel(const float* __restrict__ R,
                                                  float* __restrict__ out)
{
    const int o = blockIdx.x * 256 + threadIdx.x;     // 0..14335
    if (o >= B * NSH * 2) return;
    const int d = o & 1;
    const int s = (o >> 1) % NSH;
    const int b = (o >> 1) / NSH;
    const int node = b * 128 + NG + s;
    out[o] = R[OFF_P + node * 2 + d] + R[OFF_AGP + node * 2 + d];
}

// ---------------- launch ----------------
extern "C" void kernel_launch(void* const* d_in, const int* in_sizes, int n_in,
                              void* d_out, int out_size, void* d_ws, size_t ws_size,
                              hipStream_t stream)
{
    const float* pos      = (const float*)d_in[0];
    const int*   tsteps   = (const int*)d_in[1];
    const float* goal_pos = (const float*)d_in[2];
    const float* W_hin    = (const float*)d_in[3];
    const float* b_hin    = (const float*)d_in[4];
    const float* W_msg1   = (const float*)d_in[5];
    const float* b_msg1   = (const float*)d_in[6];
    const float* W_msg2   = (const float*)d_in[7];
    const float* b_msg2   = (const float*)d_in[8];
    const float* W_att    = (const float*)d_in[9];
    const float* b_att    = (const float*)d_in[10];
    const float* W_pos1   = (const float*)d_in[11];
    const float* b_pos1   = (const float*)d_in[12];
    const float* W_pos2   = (const float*)d_in[13];
    const float* b_pos2   = (const float*)d_in[14];
    const float* W_node1  = (const float*)d_in[15];
    const float* b_node1  = (const float*)d_in[16];
    const float* W_node2  = (const float*)d_in[17];
    const float* b_node2  = (const float*)d_in[18];
    const float* W_t      = (const float*)d_in[19];
    const float* b_t      = (const float*)d_in[20];

    float* ws = (float*)d_ws;

    constexpr int setup_threads = NN * 32 + NN * 2 + B * 32;
    setup_kernel<<<(setup_threads + 255) / 256, 256, 0, stream>>>(
        pos, tsteps, goal_pos, W_hin, b_hin, ws);

    for (int l = 0; l < L; ++l) {
        const float* tembIn = ws + ((l & 1) ? OFF_TEMB1 : OFF_TEMB0);
        pre_kernel<<<NN * 32 / 256, 256, 0, stream>>>(ws, W_msg1, b_msg1, tembIn, l);
        edge_kernel<<<2048, 256, 0, stream>>>(ws, W_msg1, W_msg2, b_msg2, W_att, b_att,
                                              W_pos1, b_pos1, W_pos2, b_pos2,
                                              ws + OFF_AGH, ws + OFF_AGP, l);
        if (l < L - 1)
            node_kernel<<<NN * 32 / 256, 256, 0, stream>>>(ws, W_node1, b_node1, W_node2,
                                                           b_node2, W_t, b_t, l);
    }
    out_kernel<<<(B * NSH * 2 + 255) / 256, 256, 0, stream>>>(ws, (float*)d_out);
}